// Round 4
// baseline (329.965 us; speedup 1.0000x reference)
//
#include <hip/hip_runtime.h>

// MultiHeadAttention (cross-head variant): out = softmax((XWq)(XWk)^T/32 per-token over heads) (XWv) Wo + bo
// Pipeline: merged cast/transpose -> fused QKV bf16 GEMM -> barrier-free per-token wave attention -> out GEMM + bias.
// R4 change: GEMM inner tile switched 16x16x32 -> 32x32x16 MFMA (17% better matrix-pipe FLOP/cyc,
//            half the MFMA instruction count, same LDS traffic). XOR bank swizzle kept.

typedef unsigned short u16;
typedef unsigned int u32;

typedef __bf16 bf16x8 __attribute__((ext_vector_type(8)));
typedef float f32x16 __attribute__((ext_vector_type(16)));

__device__ __forceinline__ u16 f2bf(float f) {
  u32 u = __float_as_uint(f);
  u += 0x7fffu + ((u >> 16) & 1u);   // round-to-nearest-even
  return (u16)(u >> 16);
}
__device__ __forceinline__ float bflo(u32 u) { return __uint_as_float(u << 16); }
__device__ __forceinline__ float bfhi(u32 u) { return __uint_as_float(u & 0xffff0000u); }

// async global->LDS, 16B per lane. LDS dest must be wave-uniform base + lane*16.
__device__ __forceinline__ void load_lds16(const u16* g, u16* l) {
  __builtin_amdgcn_global_load_lds(
      (const __attribute__((address_space(1))) u32*)g,
      (__attribute__((address_space(3))) u32*)l, 16, 0, 0);
}

// ---------------------------------------------------------------- prep (merged)
// blocks [0, 8192): cast x fp32 -> bf16, 8 elems/thread.
// blocks [8192, 12288): transpose+cast W (K x N fp32) -> Wt (N x K bf16), z = (b-8192)>>10.
__global__ __launch_bounds__(256) void prep_kernel(
    const float* __restrict__ x, u16* __restrict__ xb,
    const float* __restrict__ Wq, const float* __restrict__ Wk,
    const float* __restrict__ Wv, const float* __restrict__ Wo,
    u16* __restrict__ Wt, u16* __restrict__ Wot) {
  const int bid = blockIdx.x, tid = threadIdx.x;
  if (bid < 8192) {
    size_t i = (size_t)bid * 256 + tid;
    const float4* p = (const float4*)x;
    float4 a = p[2 * i], b = p[2 * i + 1];
    u32 w0 = (u32)f2bf(a.x) | ((u32)f2bf(a.y) << 16);
    u32 w1 = (u32)f2bf(a.z) | ((u32)f2bf(a.w) << 16);
    u32 w2 = (u32)f2bf(b.x) | ((u32)f2bf(b.y) << 16);
    u32 w3 = (u32)f2bf(b.z) | ((u32)f2bf(b.w) << 16);
    *(uint4*)(xb + 8 * i) = make_uint4(w0, w1, w2, w3);
  } else {
    __shared__ float tile[32][33];
    const int b = bid - 8192;
    const int z = b >> 10, rem = b & 1023;
    const float* W = (z == 0) ? Wq : (z == 1) ? Wk : (z == 2) ? Wv : Wo;
    u16* D = (z < 3) ? (Wt + (size_t)z * 1024 * 1024) : Wot;
    const int n0 = (rem & 31) * 32, k0 = (rem >> 5) * 32;
    const int tx = tid & 31, ty = tid >> 5;  // 32 x 8
#pragma unroll
    for (int i = 0; i < 4; i++)
      tile[ty + i * 8][tx] = W[(size_t)(k0 + ty + i * 8) * 1024 + n0 + tx];
    __syncthreads();
#pragma unroll
    for (int i = 0; i < 4; i++)
      D[(size_t)(n0 + ty + i * 8) * 1024 + k0 + tx] = f2bf(tile[tx][ty + i * 8]);
  }
}

// ---------------------------------------------------------------- GEMM (32x32x16 MFMA + swizzle)
// C[M,N] = A[M,K] * B^T where B given as Bt[N,K] (both bf16 row-major).
// WRITE_MODE 0: C bf16.  WRITE_MODE 1: C fp32 + bias.
// LDS layout: slot s holds 8 bf16 of (row = s>>3, kq = (s&7) ^ (row&7)).
// Fragments (32x32x16): A[m=lane&31][k=(lane>>5)*8+j]; C/D: col=lane&31,
// row=(reg&3)+8*(reg>>2)+4*(lane>>5)  [m74/m101 verified].
template <int WRITE_MODE>
__global__ __launch_bounds__(256) void gemm_bt(const u16* __restrict__ A,
                                               const u16* __restrict__ Bt,
                                               void* __restrict__ Cv,
                                               const float* __restrict__ bias,
                                               int N, int K) {
  constexpr int BM = 128, BN = 128, BK = 64;
  __shared__ u16 As[BM * BK];
  __shared__ u16 Bs[BN * BK];
  const int t = threadIdx.x;
  const int lane = t & 63;
  const int wave = t >> 6;
  const int wr = wave >> 1, wc = wave & 1;     // 2x2 waves, 64x64 each
  const int bm = blockIdx.y * BM, bn = blockIdx.x * BN;
  const int m32 = lane & 31;                   // row within 32-tile
  const int kh = lane >> 5;                    // k-half selector (0/1)
  const int lx = lane & 7;                     // swizzle key (== row&7 for all frag rows)

  f32x16 acc[2][2];
#pragma unroll
  for (int i = 0; i < 2; i++)
#pragma unroll
    for (int j = 0; j < 2; j++) acc[i][j] = 0.0f;

  const u16* Ap = A + (size_t)bm * K;
  const u16* Bp = Bt + (size_t)bn * K;

  // staging source offsets (swizzled): slot s = t + 256*i
  int srow[4], scol[4];
#pragma unroll
  for (int i = 0; i < 4; i++) {
    int s = t + 256 * i;
    srow[i] = s >> 3;
    scol[i] = ((s & 7) ^ (srow[i] & 7)) << 3;
  }

  for (int k0 = 0; k0 < K; k0 += BK) {
#pragma unroll
    for (int i = 0; i < 4; i++)
      load_lds16(Ap + (size_t)srow[i] * K + k0 + scol[i], &As[(t + 256 * i) * 8]);
#pragma unroll
    for (int i = 0; i < 4; i++)
      load_lds16(Bp + (size_t)srow[i] * K + k0 + scol[i], &Bs[(t + 256 * i) * 8]);
    __syncthreads();   // drains vmcnt for global_load_lds
#pragma unroll
    for (int h = 0; h < 4; h++) {               // 4 K-steps of 16
      const int kqs = ((((h << 1) + kh) ^ lx) << 3);  // swizzled 8-elem chunk offset
      bf16x8 af[2], bg[2];
#pragma unroll
      for (int g = 0; g < 2; g++)
        af[g] = *(const bf16x8*)&As[(wr * 64 + g * 32 + m32) * BK + kqs];
#pragma unroll
      for (int g = 0; g < 2; g++)
        bg[g] = *(const bf16x8*)&Bs[(wc * 64 + g * 32 + m32) * BK + kqs];
#pragma unroll
      for (int i = 0; i < 2; i++)
#pragma unroll
        for (int j = 0; j < 2; j++)
          acc[i][j] = __builtin_amdgcn_mfma_f32_32x32x16_bf16(af[i], bg[j], acc[i][j], 0, 0, 0);
    }
    __syncthreads();
  }

#pragma unroll
  for (int i = 0; i < 2; i++) {
#pragma unroll
    for (int j = 0; j < 2; j++) {
      int col = bn + wc * 64 + j * 32 + m32;
#pragma unroll
      for (int r = 0; r < 16; r++) {
        int row = bm + wr * 64 + i * 32 + (r & 3) + 8 * (r >> 2) + 4 * kh;
        if (WRITE_MODE == 0) {
          ((u16*)Cv)[(size_t)row * N + col] = f2bf(acc[i][j][r]);
        } else {
          ((float*)Cv)[(size_t)row * N + col] = acc[i][j][r] + bias[col];
        }
      }
    }
  }
}

// ---------------------------------------------------------------- attention
// One wave per token, barrier-free (each wave touches only kv[wave]).
// QKV: [tok][3072] bf16 = q(16x64) | k(16x64) | v(16x64).
// lane -> (hq = lane>>2, sub = lane&3); lane owns q[hq][sub*16..+15].
__device__ __forceinline__ void load16f(const u16* p, float* f) {
  const uint4* u = (const uint4*)p;
  uint4 a = u[0], b = u[1];
  f[0] = bflo(a.x);  f[1] = bfhi(a.x);  f[2] = bflo(a.y);  f[3] = bfhi(a.y);
  f[4] = bflo(a.z);  f[5] = bfhi(a.z);  f[6] = bflo(a.w);  f[7] = bfhi(a.w);
  f[8] = bflo(b.x);  f[9] = bfhi(b.x);  f[10] = bflo(b.y); f[11] = bfhi(b.y);
  f[12] = bflo(b.z); f[13] = bfhi(b.z); f[14] = bflo(b.w); f[15] = bfhi(b.w);
}

__global__ __launch_bounds__(256) void attn_kernel(const u16* __restrict__ QKV,
                                                   u16* __restrict__ AO) {
  __shared__ u16 kv[4][2048];  // per wave: k[0..1023], v[1024..2047]
  const int t = threadIdx.x, lane = t & 63, wave = t >> 6;
  const int sub = lane & 3;
  const int tok = blockIdx.x * 4 + wave;   // grid 4096 -> 16384 tokens

  const u16* base = QKV + (size_t)tok * 3072;
  uint4 k0 = ((const uint4*)(base + 1024))[2 * lane];
  uint4 k1 = ((const uint4*)(base + 1024))[2 * lane + 1];
  uint4 v0 = ((const uint4*)(base + 2048))[2 * lane];
  uint4 v1 = ((const uint4*)(base + 2048))[2 * lane + 1];
  float qf[16];
  load16f(base + lane * 16, qf);  // hq*64 + sub*16 == lane*16
  ((uint4*)&kv[wave][0])[2 * lane] = k0;
  ((uint4*)&kv[wave][0])[2 * lane + 1] = k1;
  ((uint4*)&kv[wave][1024])[2 * lane] = v0;
  ((uint4*)&kv[wave][1024])[2 * lane + 1] = v1;
  // no barrier: same-wave ds_write -> ds_read ordering enforced by compiler waitcnt

  float e[16];
#pragma unroll
  for (int hk = 0; hk < 16; hk++) {
    float kf[16];
    load16f(&kv[wave][hk * 64 + sub * 16], kf);
    float s = 0.f;
#pragma unroll
    for (int i = 0; i < 16; i++) s = fmaf(qf[i], kf[i], s);
    s += __shfl_xor(s, 1);
    s += __shfl_xor(s, 2);
    e[hk] = s;
  }

  float m = e[0];
#pragma unroll
  for (int hk = 1; hk < 16; hk++) m = fmaxf(m, e[hk]);
  float sum = 0.f;
#pragma unroll
  for (int hk = 0; hk < 16; hk++) {
    float p = __expf((e[hk] - m) * 0.03125f);
    e[hk] = p;
    sum += p;
  }
  float inv = 1.0f / sum;

  float o[16];
#pragma unroll
  for (int i = 0; i < 16; i++) o[i] = 0.f;
#pragma unroll
  for (int hk = 0; hk < 16; hk++) {
    float a = e[hk] * inv;
    float vf[16];
    load16f(&kv[wave][1024 + hk * 64 + sub * 16], vf);
#pragma unroll
    for (int i = 0; i < 16; i++) o[i] = fmaf(a, vf[i], o[i]);
  }

  u32 w[8];
#pragma unroll
  for (int i = 0; i < 8; i++)
    w[i] = (u32)f2bf(o[2 * i]) | ((u32)f2bf(o[2 * i + 1]) << 16);
  uint4* dst = (uint4*)(AO + (size_t)tok * 1024 + lane * 16);
  dst[0] = make_uint4(w[0], w[1], w[2], w[3]);
  dst[1] = make_uint4(w[4], w[5], w[6], w[7]);
}

// ---------------------------------------------------------------- launch

extern "C" void kernel_launch(void* const* d_in, const int* in_sizes, int n_in,
                              void* d_out, int out_size, void* d_ws, size_t ws_size,
                              hipStream_t stream) {
  const float* x = (const float*)d_in[0];
  const float* Wq = (const float*)d_in[1];
  const float* Wk = (const float*)d_in[2];
  const float* Wv = (const float*)d_in[3];
  const float* Wo = (const float*)d_in[4];
  const float* bo = (const float*)d_in[5];
  float* out = (float*)d_out;

  char* ws = (char*)d_ws;
  u16* Xb  = (u16*)(ws);                    // 16384*1024*2 = 33,554,432
  u16* Wt  = (u16*)(ws + 33554432);         // 3072*1024*2  =  6,291,456
  u16* Wot = (u16*)(ws + 39845888);         // 1024*1024*2  =  2,097,152
  u16* QKV = (u16*)(ws + 41943040);         // 16384*3072*2 = 100,663,296
  u16* AO  = (u16*)(ws + 142606336);        // 16384*1024*2 = 33,554,432  (total 176,160,768)

  prep_kernel<<<12288, 256, 0, stream>>>(x, Xb, Wq, Wk, Wv, Wo, Wt, Wot);
  gemm_bt<0><<<dim3(24, 128), 256, 0, stream>>>(Xb, Wt, QKV, nullptr, 3072, 1024);
  attn_kernel<<<4096, 256, 0, stream>>>(QKV, AO);
  gemm_bt<1><<<dim3(8, 128), 256, 0, stream>>>(AO, Wot, out, bo, 1024, 1024);
}

// Round 5
// 324.619 us; speedup vs baseline: 1.0165x; 1.0165x over previous
//
#include <hip/hip_runtime.h>

// MultiHeadAttention (cross-head variant): out = softmax((XWq)(XWk)^T/32 per-token over heads) (XWv) Wo + bo
// Pipeline: merged cast/transpose -> fused QKV bf16 GEMM (m97 + XOR swizzle, 16x16x32) ->
//           barrier-free per-token wave attention -> out GEMM + bias.
// R5 changes: (a) revert GEMM to 16x16x32 MFMA (R4's 32x32x16 was neutral: conflicts returned,
//             not MFMA-issue-bound); (b) XCD-aware block remap in both GEMMs so blocks sharing
//             an A row-panel land on one XCD's L2 (16 panels x 256 KB = 4 MB = one L2).

typedef unsigned short u16;
typedef unsigned int u32;

typedef __bf16 bf16x8 __attribute__((ext_vector_type(8)));
typedef float f32x4 __attribute__((ext_vector_type(4)));

__device__ __forceinline__ u16 f2bf(float f) {
  u32 u = __float_as_uint(f);
  u += 0x7fffu + ((u >> 16) & 1u);   // round-to-nearest-even
  return (u16)(u >> 16);
}
__device__ __forceinline__ float bflo(u32 u) { return __uint_as_float(u << 16); }
__device__ __forceinline__ float bfhi(u32 u) { return __uint_as_float(u & 0xffff0000u); }

// async global->LDS, 16B per lane. LDS dest must be wave-uniform base + lane*16.
__device__ __forceinline__ void load_lds16(const u16* g, u16* l) {
  __builtin_amdgcn_global_load_lds(
      (const __attribute__((address_space(1))) u32*)g,
      (__attribute__((address_space(3))) u32*)l, 16, 0, 0);
}

// ---------------------------------------------------------------- prep (merged)
// blocks [0, 8192): cast x fp32 -> bf16, 8 elems/thread.
// blocks [8192, 12288): transpose+cast W (K x N fp32) -> Wt (N x K bf16), z = (b-8192)>>10.
__global__ __launch_bounds__(256) void prep_kernel(
    const float* __restrict__ x, u16* __restrict__ xb,
    const float* __restrict__ Wq, const float* __restrict__ Wk,
    const float* __restrict__ Wv, const float* __restrict__ Wo,
    u16* __restrict__ Wt, u16* __restrict__ Wot) {
  const int bid = blockIdx.x, tid = threadIdx.x;
  if (bid < 8192) {
    size_t i = (size_t)bid * 256 + tid;
    const float4* p = (const float4*)x;
    float4 a = p[2 * i], b = p[2 * i + 1];
    u32 w0 = (u32)f2bf(a.x) | ((u32)f2bf(a.y) << 16);
    u32 w1 = (u32)f2bf(a.z) | ((u32)f2bf(a.w) << 16);
    u32 w2 = (u32)f2bf(b.x) | ((u32)f2bf(b.y) << 16);
    u32 w3 = (u32)f2bf(b.z) | ((u32)f2bf(b.w) << 16);
    *(uint4*)(xb + 8 * i) = make_uint4(w0, w1, w2, w3);
  } else {
    __shared__ float tile[32][33];
    const int b = bid - 8192;
    const int z = b >> 10, rem = b & 1023;
    const float* W = (z == 0) ? Wq : (z == 1) ? Wk : (z == 2) ? Wv : Wo;
    u16* D = (z < 3) ? (Wt + (size_t)z * 1024 * 1024) : Wot;
    const int n0 = (rem & 31) * 32, k0 = (rem >> 5) * 32;
    const int tx = tid & 31, ty = tid >> 5;  // 32 x 8
#pragma unroll
    for (int i = 0; i < 4; i++)
      tile[ty + i * 8][tx] = W[(size_t)(k0 + ty + i * 8) * 1024 + n0 + tx];
    __syncthreads();
#pragma unroll
    for (int i = 0; i < 4; i++)
      D[(size_t)(n0 + ty + i * 8) * 1024 + k0 + tx] = f2bf(tile[tx][ty + i * 8]);
  }
}

// ---------------------------------------------------------------- GEMM (m97 + swizzle + XCD remap)
// C[M,N] = A[M,K] * B^T where B given as Bt[N,K] (both bf16 row-major). M fixed = 16384 (128 bm tiles).
// WRITE_MODE 0: C bf16.  WRITE_MODE 1: C fp32 + bias.
// LDS layout: slot s holds 8 bf16 of (row = s>>3, kq = (s&7) ^ (row&7)).
// Block remap: flat bid -> bm_tile = (bid&7)*16 + ((bid>>3)&15), bn_tile = bid>>7.
// With XCD = bid%8 dispatch heuristic, each XCD sees 16 contiguous A row-panels (4 MB = its L2).
template <int WRITE_MODE>
__global__ __launch_bounds__(256) void gemm_bt(const u16* __restrict__ A,
                                               const u16* __restrict__ Bt,
                                               void* __restrict__ Cv,
                                               const float* __restrict__ bias,
                                               int N, int K) {
  constexpr int BM = 128, BN = 128, BK = 64;
  __shared__ u16 As[BM * BK];
  __shared__ u16 Bs[BN * BK];
  const int t = threadIdx.x;
  const int lane = t & 63;
  const int wave = t >> 6;
  const int wr = wave >> 1, wc = wave & 1;     // 2x2 waves, 64x64 each
  const int bid = blockIdx.x;
  const int bm = (((bid & 7) << 4) + ((bid >> 3) & 15)) * BM;
  const int bn = (bid >> 7) * BN;
  const int lrow = lane & 15, lq = lane >> 4;
  const int lx = lrow & 7;                      // swizzle key for fragment reads

  f32x4 acc[4][4];
#pragma unroll
  for (int i = 0; i < 4; i++)
#pragma unroll
    for (int j = 0; j < 4; j++) acc[i][j] = 0.0f;

  const u16* Ap = A + (size_t)bm * K;
  const u16* Bp = Bt + (size_t)bn * K;

  int srow[4], scol[4];
#pragma unroll
  for (int i = 0; i < 4; i++) {
    int s = t + 256 * i;
    srow[i] = s >> 3;
    scol[i] = ((s & 7) ^ (srow[i] & 7)) << 3;
  }

  for (int k0 = 0; k0 < K; k0 += BK) {
#pragma unroll
    for (int i = 0; i < 4; i++)
      load_lds16(Ap + (size_t)srow[i] * K + k0 + scol[i], &As[(t + 256 * i) * 8]);
#pragma unroll
    for (int i = 0; i < 4; i++)
      load_lds16(Bp + (size_t)srow[i] * K + k0 + scol[i], &Bs[(t + 256 * i) * 8]);
    __syncthreads();   // drains vmcnt for global_load_lds
#pragma unroll
    for (int ks = 0; ks < BK; ks += 32) {
      const int kq = (ks >> 3) + lq;            // 0..7
      const int kqs = (kq ^ lx) << 3;           // swizzled k-chunk offset (elems)
      bf16x8 af[4], bg[4];
#pragma unroll
      for (int i = 0; i < 4; i++)
        af[i] = *(const bf16x8*)&As[(wr * 64 + i * 16 + lrow) * BK + kqs];
#pragma unroll
      for (int j = 0; j < 4; j++)
        bg[j] = *(const bf16x8*)&Bs[(wc * 64 + j * 16 + lrow) * BK + kqs];
#pragma unroll
      for (int i = 0; i < 4; i++)
#pragma unroll
        for (int j = 0; j < 4; j++)
          acc[i][j] = __builtin_amdgcn_mfma_f32_16x16x32_bf16(af[i], bg[j], acc[i][j], 0, 0, 0);
    }
    __syncthreads();
  }

  // C/D layout: col = lane&15, row = (lane>>4)*4 + r  [verified m89/m91]
#pragma unroll
  for (int i = 0; i < 4; i++) {
#pragma unroll
    for (int j = 0; j < 4; j++) {
      int col = bn + wc * 64 + j * 16 + lrow;
#pragma unroll
      for (int r = 0; r < 4; r++) {
        int row = bm + wr * 64 + i * 16 + lq * 4 + r;
        if (WRITE_MODE == 0) {
          ((u16*)Cv)[(size_t)row * N + col] = f2bf(acc[i][j][r]);
        } else {
          ((float*)Cv)[(size_t)row * N + col] = acc[i][j][r] + bias[col];
        }
      }
    }
  }
}

// ---------------------------------------------------------------- attention
// One wave per token, barrier-free (each wave touches only kv[wave]).
// QKV: [tok][3072] bf16 = q(16x64) | k(16x64) | v(16x64).
// lane -> (hq = lane>>2, sub = lane&3); lane owns q[hq][sub*16..+15].
__device__ __forceinline__ void load16f(const u16* p, float* f) {
  const uint4* u = (const uint4*)p;
  uint4 a = u[0], b = u[1];
  f[0] = bflo(a.x);  f[1] = bfhi(a.x);  f[2] = bflo(a.y);  f[3] = bfhi(a.y);
  f[4] = bflo(a.z);  f[5] = bfhi(a.z);  f[6] = bflo(a.w);  f[7] = bfhi(a.w);
  f[8] = bflo(b.x);  f[9] = bfhi(b.x);  f[10] = bflo(b.y); f[11] = bfhi(b.y);
  f[12] = bflo(b.z); f[13] = bfhi(b.z); f[14] = bflo(b.w); f[15] = bfhi(b.w);
}

__global__ __launch_bounds__(256) void attn_kernel(const u16* __restrict__ QKV,
                                                   u16* __restrict__ AO) {
  __shared__ u16 kv[4][2048];  // per wave: k[0..1023], v[1024..2047]
  const int t = threadIdx.x, lane = t & 63, wave = t >> 6;
  const int sub = lane & 3;
  const int tok = blockIdx.x * 4 + wave;   // grid 4096 -> 16384 tokens

  const u16* base = QKV + (size_t)tok * 3072;
  uint4 k0 = ((const uint4*)(base + 1024))[2 * lane];
  uint4 k1 = ((const uint4*)(base + 1024))[2 * lane + 1];
  uint4 v0 = ((const uint4*)(base + 2048))[2 * lane];
  uint4 v1 = ((const uint4*)(base + 2048))[2 * lane + 1];
  float qf[16];
  load16f(base + lane * 16, qf);  // hq*64 + sub*16 == lane*16
  ((uint4*)&kv[wave][0])[2 * lane] = k0;
  ((uint4*)&kv[wave][0])[2 * lane + 1] = k1;
  ((uint4*)&kv[wave][1024])[2 * lane] = v0;
  ((uint4*)&kv[wave][1024])[2 * lane + 1] = v1;
  // no barrier: same-wave ds_write -> ds_read ordering enforced by compiler waitcnt

  float e[16];
#pragma unroll
  for (int hk = 0; hk < 16; hk++) {
    float kf[16];
    load16f(&kv[wave][hk * 64 + sub * 16], kf);
    float s = 0.f;
#pragma unroll
    for (int i = 0; i < 16; i++) s = fmaf(qf[i], kf[i], s);
    s += __shfl_xor(s, 1);
    s += __shfl_xor(s, 2);
    e[hk] = s;
  }

  float m = e[0];
#pragma unroll
  for (int hk = 1; hk < 16; hk++) m = fmaxf(m, e[hk]);
  float sum = 0.f;
#pragma unroll
  for (int hk = 0; hk < 16; hk++) {
    float p = __expf((e[hk] - m) * 0.03125f);
    e[hk] = p;
    sum += p;
  }
  float inv = 1.0f / sum;

  float o[16];
#pragma unroll
  for (int i = 0; i < 16; i++) o[i] = 0.f;
#pragma unroll
  for (int hk = 0; hk < 16; hk++) {
    float a = e[hk] * inv;
    float vf[16];
    load16f(&kv[wave][1024 + hk * 64 + sub * 16], vf);
#pragma unroll
    for (int i = 0; i < 16; i++) o[i] = fmaf(a, vf[i], o[i]);
  }

  u32 w[8];
#pragma unroll
  for (int i = 0; i < 8; i++)
    w[i] = (u32)f2bf(o[2 * i]) | ((u32)f2bf(o[2 * i + 1]) << 16);
  uint4* dst = (uint4*)(AO + (size_t)tok * 1024 + lane * 16);
  dst[0] = make_uint4(w[0], w[1], w[2], w[3]);
  dst[1] = make_uint4(w[4], w[5], w[6], w[7]);
}

// ---------------------------------------------------------------- launch

extern "C" void kernel_launch(void* const* d_in, const int* in_sizes, int n_in,
                              void* d_out, int out_size, void* d_ws, size_t ws_size,
                              hipStream_t stream) {
  const float* x = (const float*)d_in[0];
  const float* Wq = (const float*)d_in[1];
  const float* Wk = (const float*)d_in[2];
  const float* Wv = (const float*)d_in[3];
  const float* Wo = (const float*)d_in[4];
  const float* bo = (const float*)d_in[5];
  float* out = (float*)d_out;

  char* ws = (char*)d_ws;
  u16* Xb  = (u16*)(ws);                    // 16384*1024*2 = 33,554,432
  u16* Wt  = (u16*)(ws + 33554432);         // 3072*1024*2  =  6,291,456
  u16* Wot = (u16*)(ws + 39845888);         // 1024*1024*2  =  2,097,152
  u16* QKV = (u16*)(ws + 41943040);         // 16384*3072*2 = 100,663,296
  u16* AO  = (u16*)(ws + 142606336);        // 16384*1024*2 = 33,554,432  (total 176,160,768)

  prep_kernel<<<12288, 256, 0, stream>>>(x, Xb, Wq, Wk, Wv, Wo, Wt, Wot);
  gemm_bt<0><<<3072, 256, 0, stream>>>(Xb, Wt, QKV, nullptr, 3072, 1024);
  attn_kernel<<<4096, 256, 0, stream>>>(QKV, AO);
  gemm_bt<1><<<1024, 256, 0, stream>>>(AO, Wot, out, bo, 1024, 1024);
}